// Round 2
// baseline (815.212 us; speedup 1.0000x reference)
//
#include <hip/hip_runtime.h>
#include <math.h>

// Problem constants (match reference):
#define BB    2
#define NN    8192
#define DD    256
#define NBINS 32
#define BINSZ 256
#define NPROJ 16     // n_bins // 2
#define TOPK  16
#define NPTS  (BB * NN)   // 16384

// ---------------------------------------------------------------------------
// K1: bin assignment. One wave per block; codebook (first 16 cols) in LDS.
// fp64 accumulation -> fp32 compare reproduces the fp32 reference exactly
// (absmax 0.0 in round 1 — do not touch the numerics).
// ---------------------------------------------------------------------------
__global__ __launch_bounds__(64) void k_bins(const float* __restrict__ x,
                                             const float* __restrict__ cb,
                                             int* __restrict__ bin_idx) {
    __shared__ float cbt[DD][NPROJ];   // 16 KB
    const int t = threadIdx.x;         // 0..63
    // codebook is (256, 32); we need cols 0..15 of each row -> 4 float4/row
    for (int q = t; q < DD * 4; q += 64) {
        int d = q >> 2, j4 = q & 3;
        float4 v = *(const float4*)(cb + d * 32 + j4 * 4);
        cbt[d][j4 * 4 + 0] = v.x; cbt[d][j4 * 4 + 1] = v.y;
        cbt[d][j4 * 4 + 2] = v.z; cbt[d][j4 * 4 + 3] = v.w;
    }
    __syncthreads();

    const int p = blockIdx.x * 64 + t;            // 0..16383 (flat over B,N)
    const float* xr = x + (size_t)p * DD;

    double a[NPROJ];
#pragma unroll
    for (int j = 0; j < NPROJ; ++j) a[j] = 0.0;

    for (int d0 = 0; d0 < DD; d0 += 4) {
        float4 xv = *(const float4*)(xr + d0);
        float xs[4] = {xv.x, xv.y, xv.z, xv.w};
#pragma unroll
        for (int dd = 0; dd < 4; ++dd) {
            double xd = (double)xs[dd];
#pragma unroll
            for (int j = 0; j < NPROJ; ++j)
                a[j] = fma((double)cbt[d0 + dd][j], xd, a[j]);
        }
    }

    // argmax over cmul = [m0..m15, -m0..-m15], first occurrence of max.
    float bv = -INFINITY; int bj = 0;
#pragma unroll
    for (int j = 0; j < NPROJ; ++j) {
        float m = (float)a[j];
        if (m > bv) { bv = m; bj = j; }
    }
#pragma unroll
    for (int j = 0; j < NPROJ; ++j) {
        float m = -(float)a[j];
        if (m > bv) { bv = m; bj = j + NPROJ; }
    }
    bin_idx[p] = bj;
}

// ---------------------------------------------------------------------------
// K2: stable counting sort (== stable argsort of bin ids). One block per batch.
// ---------------------------------------------------------------------------
__global__ __launch_bounds__(256) void k_sort(const int* __restrict__ bin_idx,
                                              int* __restrict__ order) {
    __shared__ int c[NBINS][256];   // 32 KB
    __shared__ int base[NBINS];
    const int t = threadIdx.x;
    const int b = blockIdx.x;
    const int* bi = bin_idx + b * NN;

    for (int j = 0; j < NBINS; ++j) c[j][t] = 0;
    __syncthreads();

    const int i0 = t * 32;
    for (int i = 0; i < 32; ++i) c[bi[i0 + i]][t]++;
    __syncthreads();

    if (t < NBINS) {                 // per-bin totals
        int s = 0;
        for (int q = 0; q < 256; ++q) s += c[t][q];
        base[t] = s;
    }
    __syncthreads();
    if (t == 0) {                    // exclusive prefix over bins
        int run = 0;
        for (int j = 0; j < NBINS; ++j) { int tmp = base[j]; base[j] = run; run += tmp; }
    }
    __syncthreads();
    if (t < NBINS) {                 // exclusive prefix over threads within bin
        int run = base[t];
        for (int q = 0; q < 256; ++q) { int tmp = c[t][q]; c[t][q] = run; run += tmp; }
    }
    __syncthreads();

    int* ob = order + b * NN;
    for (int i = 0; i < 32; ++i) {
        int gi = i0 + i;
        int bb = bi[gi];
        int pos = c[bb][t]++;        // column t is thread-exclusive
        ob[pos] = gi;
    }
}

// ---------------------------------------------------------------------------
// K3 (fused): per (batch, bin, 32-row tile):
//   phase 0: fire-and-forget zero stores for this block's 32 output rows
//            (1 MB/block; replaces the 350us rocclr fill and overlaps compute)
//   phase 1: S = P P^T rows in fp64, sigmoid to fp32
//   phase 2: exact top-16 (desc value, ties -> lowest index)
//   phase 3: barrier (zero stores drained via vmcnt(0) before s_barrier),
//            then scatter the 512 values into the already-zeroed rows.
// Block = 256 threads (one per column). grid = 2*32*8 = 512 -> 2 blocks/CU.
// ---------------------------------------------------------------------------
#define RT 32
__global__ __launch_bounds__(256, 2) void k_sim(const float* __restrict__ x,
                                                const int* __restrict__ order,
                                                float* __restrict__ out) {
    __shared__ int    idx[BINSZ];            // 1 KB
    __shared__ double Ad[RT][33];            // 8.25 KB (pad -> conflict-free)
    __shared__ float  S[RT][BINSZ + 1];      // ~33 KB
    __shared__ float  tvs[RT][TOPK];         // 2 KB
    __shared__ int    tds[RT][TOPK];         // 2 KB (global dst indices)

    const int t   = threadIdx.x;
    const int bid = blockIdx.x;              // 0..511
    const int b   = bid >> 8;
    const int bin = (bid >> 3) & 31;
    const int r0  = (bid & 7) * RT;

    idx[t] = order[b * NN + bin * BINSZ + t];
    __syncthreads();

    // ---- phase 0: zero this block's 32 output rows (fire-and-forget) ----
    {
        const float4 z = make_float4(0.f, 0.f, 0.f, 0.f);
#pragma unroll 1
        for (int r = 0; r < RT; ++r) {
            float4* orow = (float4*)(out + ((size_t)b * NN + idx[r0 + r]) * NN);
#pragma unroll
            for (int j = 0; j < 8; ++j)
                orow[j * 256 + t] = z;       // wave-contiguous 1KB per instr
        }
    }

    // ---- phase 1: fp64 GEMM rows r0..r0+31 x all 256 cols ----
    const float* xb = x + (size_t)b * NN * DD;
    const float* xc = xb + (size_t)idx[t] * DD;   // my column's point row

    double acc[RT];
#pragma unroll
    for (int r = 0; r < RT; ++r) acc[r] = 0.0;

#pragma unroll 1
    for (int k0 = 0; k0 < DD; k0 += 32) {
        float bcol[32];
#pragma unroll
        for (int q = 0; q < 8; ++q) {
            float4 v = *(const float4*)(xc + k0 + q * 4);
            bcol[q * 4 + 0] = v.x; bcol[q * 4 + 1] = v.y;
            bcol[q * 4 + 2] = v.z; bcol[q * 4 + 3] = v.w;
        }
        {
            int r  = t >> 3;
            int qg = t & 7;
            const float* ar = xb + (size_t)idx[r0 + r] * DD + k0 + qg * 4;
            float4 v = *(const float4*)ar;
            Ad[r][qg * 4 + 0] = (double)v.x;
            Ad[r][qg * 4 + 1] = (double)v.y;
            Ad[r][qg * 4 + 2] = (double)v.z;
            Ad[r][qg * 4 + 3] = (double)v.w;
        }
        __syncthreads();
#pragma unroll
        for (int dd = 0; dd < 32; ++dd) {
            double bd = (double)bcol[dd];
#pragma unroll
            for (int r = 0; r < RT; ++r)
                acc[r] = fma(Ad[r][dd], bd, acc[r]);   // A broadcast from LDS
        }
        __syncthreads();
    }

    // sigmoid in the reference's fp32 chain
#pragma unroll
    for (int r = 0; r < RT; ++r) {
        float s32 = (float)acc[r];
        S[r][t] = 1.0f / (1.0f + expf(-s32));
    }
    __syncthreads();

    // ---- phase 2: top-16 per row (desc value, ties -> lowest index) ----
    if (t < RT) {
        float tv[TOPK]; int ti[TOPK];
#pragma unroll
        for (int q = 0; q < TOPK; ++q) { tv[q] = -INFINITY; ti[q] = 0; }
        for (int cc = 0; cc < BINSZ; ++cc) {
            float v = S[t][cc];
            if (v > tv[TOPK - 1]) {          // strict >: equal keeps earlier idx
                tv[TOPK - 1] = v; ti[TOPK - 1] = cc;
#pragma unroll
                for (int q = TOPK - 1; q > 0; --q) {
                    if (tv[q] > tv[q - 1]) { // strict >: stable among equals
                        float fv = tv[q]; tv[q] = tv[q - 1]; tv[q - 1] = fv;
                        int   fi = ti[q]; ti[q] = ti[q - 1]; ti[q - 1] = fi;
                    }
                }
            }
        }
#pragma unroll
        for (int q = 0; q < TOPK; ++q) {
            tvs[t][q] = tv[q];
            tds[t][q] = idx[ti[q]];          // map local col -> global point id
        }
    }
    // Barrier: compiler emits s_waitcnt vmcnt(0) before s_barrier, so the
    // phase-0 zero stores are committed before the value stores below.
    __syncthreads();

    // ---- phase 3: scatter 512 values into the zeroed rows ----
#pragma unroll
    for (int p = t; p < RT * TOPK; p += 256) {
        int r = p >> 4, q = p & 15;
        float* orow = out + ((size_t)b * NN + idx[r0 + r]) * NN;
        orow[tds[r][q]] = tvs[r][q];         // all (src,dst) unique -> plain store
    }
}

// ---------------------------------------------------------------------------
extern "C" void kernel_launch(void* const* d_in, const int* in_sizes, int n_in,
                              void* d_out, int out_size, void* d_ws, size_t ws_size,
                              hipStream_t stream) {
    const float* x  = (const float*)d_in[0];
    const float* cb = (const float*)d_in[1];
    float* out      = (float*)d_out;

    int* bin_idx = (int*)d_ws;           // NPTS ints
    int* order   = bin_idx + NPTS;       // NPTS ints  (needs 128 KB of ws)

    // NOTE: no memset — k_sim writes every output element (bins_split is a
    // permutation, so the 512 blocks' 32-row sets tile the output exactly).
    k_bins<<<NPTS / 64, 64, 0, stream>>>(x, cb, bin_idx);
    k_sort<<<BB, 256, 0, stream>>>(bin_idx, order);
    k_sim<<<BB * NBINS * 8, 256, 0, stream>>>(x, order, out);
}

// Round 4
// 680.904 us; speedup vs baseline: 1.1972x; 1.1972x over previous
//
#include <hip/hip_runtime.h>
#include <math.h>

// Problem constants (match reference):
#define BB    2
#define NN    8192
#define DD    256
#define NBINS 32
#define BINSZ 256
#define NPROJ 16     // n_bins // 2
#define TOPK  16
#define NPTS  (BB * NN)   // 16384

typedef float vf4 __attribute__((ext_vector_type(4)));  // native vec for nt-store

// ---------------------------------------------------------------------------
// K1: bin assignment (unchanged — absmax 0.0, do not touch numerics).
// ---------------------------------------------------------------------------
__global__ __launch_bounds__(64) void k_bins(const float* __restrict__ x,
                                             const float* __restrict__ cb,
                                             int* __restrict__ bin_idx) {
    __shared__ float cbt[DD][NPROJ];   // 16 KB
    const int t = threadIdx.x;         // 0..63
    for (int q = t; q < DD * 4; q += 64) {
        int d = q >> 2, j4 = q & 3;
        float4 v = *(const float4*)(cb + d * 32 + j4 * 4);
        cbt[d][j4 * 4 + 0] = v.x; cbt[d][j4 * 4 + 1] = v.y;
        cbt[d][j4 * 4 + 2] = v.z; cbt[d][j4 * 4 + 3] = v.w;
    }
    __syncthreads();

    const int p = blockIdx.x * 64 + t;            // 0..16383 (flat over B,N)
    const float* xr = x + (size_t)p * DD;

    double a[NPROJ];
#pragma unroll
    for (int j = 0; j < NPROJ; ++j) a[j] = 0.0;

    for (int d0 = 0; d0 < DD; d0 += 4) {
        float4 xv = *(const float4*)(xr + d0);
        float xs[4] = {xv.x, xv.y, xv.z, xv.w};
#pragma unroll
        for (int dd = 0; dd < 4; ++dd) {
            double xd = (double)xs[dd];
#pragma unroll
            for (int j = 0; j < NPROJ; ++j)
                a[j] = fma((double)cbt[d0 + dd][j], xd, a[j]);
        }
    }

    float bv = -INFINITY; int bj = 0;
#pragma unroll
    for (int j = 0; j < NPROJ; ++j) {
        float m = (float)a[j];
        if (m > bv) { bv = m; bj = j; }
    }
#pragma unroll
    for (int j = 0; j < NPROJ; ++j) {
        float m = -(float)a[j];
        if (m > bv) { bv = m; bj = j + NPROJ; }
    }
    bin_idx[p] = bj;
}

// ---------------------------------------------------------------------------
// K2: stable counting sort (unchanged).
// ---------------------------------------------------------------------------
__global__ __launch_bounds__(256) void k_sort(const int* __restrict__ bin_idx,
                                              int* __restrict__ order) {
    __shared__ int c[NBINS][256];   // 32 KB
    __shared__ int base[NBINS];
    const int t = threadIdx.x;
    const int b = blockIdx.x;
    const int* bi = bin_idx + b * NN;

    for (int j = 0; j < NBINS; ++j) c[j][t] = 0;
    __syncthreads();

    const int i0 = t * 32;
    for (int i = 0; i < 32; ++i) c[bi[i0 + i]][t]++;
    __syncthreads();

    if (t < NBINS) {
        int s = 0;
        for (int q = 0; q < 256; ++q) s += c[t][q];
        base[t] = s;
    }
    __syncthreads();
    if (t == 0) {
        int run = 0;
        for (int j = 0; j < NBINS; ++j) { int tmp = base[j]; base[j] = run; run += tmp; }
    }
    __syncthreads();
    if (t < NBINS) {
        int run = base[t];
        for (int q = 0; q < 256; ++q) { int tmp = c[t][q]; c[t][q] = run; run += tmp; }
    }
    __syncthreads();

    int* ob = order + b * NN;
    for (int i = 0; i < 32; ++i) {
        int gi = i0 + i;
        int bb = bi[gi];
        int pos = c[bb][t]++;
        ob[pos] = gi;
    }
}

// ---------------------------------------------------------------------------
// K3 (fused, restructured):
//  - thread t owns 16 rows (half rh = t>>7) x 2 cols (c = t&127, c+128)
//  - A tile staged as fp32 in LDS; float4 LDS reads (4 dims) feed 8 fp64 FMAs
//    -> DS instrs cut 8x vs round-2 (1024 vs 8192 per thread)
//  - fp64 accumulation in strictly increasing dd order (bit-identical to np ref)
//  - 4 output rows zero-stored (nontemporal) per K-chunk, loads issued before
//    stores each iter so load-waits never drain the store queue (in-order vmcnt)
// grid = 2*32*8 = 512 blocks -> 2 blocks/CU. LDS ~42.4 KB.
// ---------------------------------------------------------------------------
#define RT 32
__global__ __launch_bounds__(256, 2) void k_sim(const float* __restrict__ x,
                                                const int* __restrict__ order,
                                                float* __restrict__ out) {
    __shared__ int   idx[BINSZ];            // 1 KB
    __shared__ float Af[RT][36];            // 4.5 KB fp32 A-tile (36: 16B-aligned rows)
    __shared__ float S[RT][BINSZ + 1];      // ~32.9 KB
    __shared__ float tvs[RT][TOPK];         // 2 KB
    __shared__ int   tds[RT][TOPK];         // 2 KB

    const int t   = threadIdx.x;
    const int bid = blockIdx.x;              // 0..511
    const int b   = bid >> 8;
    const int bin = (bid >> 3) & 31;
    const int r0  = (bid & 7) * RT;

    idx[t] = order[b * NN + bin * BINSZ + t];
    __syncthreads();

    const int rh = t >> 7;                   // 0/1: rows rh*16 .. rh*16+15
    const int c  = t & 127;                  // cols c and c+128
    const float* xb  = x + (size_t)b * NN * DD;
    const float* xc0 = xb + (size_t)idx[c] * DD;
    const float* xc1 = xb + (size_t)idx[c + 128] * DD;

    const int sr = t >> 3;                   // staging: row 0..31
    const int qg = t & 7;                    // staging: float4 slot 0..7
    const float* arow = xb + (size_t)idx[r0 + sr] * DD + qg * 4;

    double acc[16][2];
#pragma unroll
    for (int r = 0; r < 16; ++r) { acc[r][0] = 0.0; acc[r][1] = 0.0; }

    const vf4 z4 = (vf4)0.0f;

#pragma unroll 1
    for (int it = 0; it < 8; ++it) {
        const int k0 = it * 32;

        // ---- global LOADS first (A-stage fragment + 2 B-col chunks) ----
        float4 av = *(const float4*)(arow + k0);
        float4 b0v[8], b1v[8];
#pragma unroll
        for (int q = 0; q < 8; ++q) b0v[q] = *(const float4*)(xc0 + k0 + q * 4);
#pragma unroll
        for (int q = 0; q < 8; ++q) b1v[q] = *(const float4*)(xc1 + k0 + q * 4);

        // ---- zero 4 of this block's 32 output rows (fire-and-forget, nt) ----
        {
            const int zr = it * 4;
#pragma unroll
            for (int rr = 0; rr < 4; ++rr) {
                vf4* orow = (vf4*)(out + ((size_t)b * NN + idx[r0 + zr + rr]) * NN);
#pragma unroll
                for (int j = 0; j < 8; ++j)
                    __builtin_nontemporal_store(z4, orow + j * 256 + t);
            }
        }

        // ---- stage A tile (fp32) into LDS ----
        *(float4*)&Af[sr][qg * 4] = av;
        __syncthreads();

        // ---- fp64 FMA: 16 rows x 2 cols, dd strictly increasing ----
#pragma unroll
        for (int dd4 = 0; dd4 < 8; ++dd4) {
            const float4 bq0 = b0v[dd4], bq1 = b1v[dd4];
            const double c00 = (double)bq0.x, c01 = (double)bq0.y,
                         c02 = (double)bq0.z, c03 = (double)bq0.w;
            const double c10 = (double)bq1.x, c11 = (double)bq1.y,
                         c12 = (double)bq1.z, c13 = (double)bq1.w;
#pragma unroll
            for (int r = 0; r < 16; ++r) {
                const float4 afv = *(const float4*)&Af[rh * 16 + r][dd4 * 4];
                const double a0 = (double)afv.x, a1 = (double)afv.y,
                             a2 = (double)afv.z, a3 = (double)afv.w;
                double s0 = acc[r][0];
                s0 = fma(a0, c00, s0); s0 = fma(a1, c01, s0);
                s0 = fma(a2, c02, s0); s0 = fma(a3, c03, s0);
                acc[r][0] = s0;
                double s1 = acc[r][1];
                s1 = fma(a0, c10, s1); s1 = fma(a1, c11, s1);
                s1 = fma(a2, c12, s1); s1 = fma(a3, c13, s1);
                acc[r][1] = s1;
            }
        }
        __syncthreads();
    }

    // ---- sigmoid (reference fp32 chain) -> S ----
#pragma unroll
    for (int r = 0; r < 16; ++r) {
        float s0 = (float)acc[r][0];
        S[rh * 16 + r][c]       = 1.0f / (1.0f + expf(-s0));
        float s1 = (float)acc[r][1];
        S[rh * 16 + r][c + 128] = 1.0f / (1.0f + expf(-s1));
    }
    __syncthreads();

    // ---- top-16 per row (desc value, ties -> lowest index) ----
    if (t < RT) {
        float tv[TOPK]; int ti[TOPK];
#pragma unroll
        for (int q = 0; q < TOPK; ++q) { tv[q] = -INFINITY; ti[q] = 0; }
        for (int cc = 0; cc < BINSZ; ++cc) {
            float v = S[t][cc];
            if (v > tv[TOPK - 1]) {
                tv[TOPK - 1] = v; ti[TOPK - 1] = cc;
#pragma unroll
                for (int q = TOPK - 1; q > 0; --q) {
                    if (tv[q] > tv[q - 1]) {
                        float fv = tv[q]; tv[q] = tv[q - 1]; tv[q - 1] = fv;
                        int   fi = ti[q]; ti[q] = ti[q - 1]; ti[q - 1] = fi;
                    }
                }
            }
        }
#pragma unroll
        for (int q = 0; q < TOPK; ++q) {
            tvs[t][q] = tv[q];
            tds[t][q] = idx[ti[q]];
        }
    }
    // barrier drains vmcnt(0): all zero stores committed before scatter below
    __syncthreads();

    // ---- scatter 512 values into the zeroed rows ----
#pragma unroll
    for (int p = t; p < RT * TOPK; p += 256) {
        int r = p >> 4, q = p & 15;
        float* orow = out + ((size_t)b * NN + idx[r0 + r]) * NN;
        orow[tds[r][q]] = tvs[r][q];
    }
}

// ---------------------------------------------------------------------------
extern "C" void kernel_launch(void* const* d_in, const int* in_sizes, int n_in,
                              void* d_out, int out_size, void* d_ws, size_t ws_size,
                              hipStream_t stream) {
    const float* x  = (const float*)d_in[0];
    const float* cb = (const float*)d_in[1];
    float* out      = (float*)d_out;

    int* bin_idx = (int*)d_ws;           // NPTS ints
    int* order   = bin_idx + NPTS;       // NPTS ints

    k_bins<<<NPTS / 64, 64, 0, stream>>>(x, cb, bin_idx);
    k_sort<<<BB, 256, 0, stream>>>(bin_idx, order);
    k_sim<<<BB * NBINS * 8, 256, 0, stream>>>(x, order, out);
}